// Round 1
// baseline (252.572 us; speedup 1.0000x reference)
//
#include <hip/hip_runtime.h>

#define B 256
#define N 512
#define M 512

// ---------------------------------------------------------------------------
// K1: sum_x[n] = sum_b x[b,n]; sum_w[m] = sum_n w[n,m]. f64 accumulate.
// 1024 threads total, coalesced across lanes (adjacent lanes -> adjacent cols).
// ---------------------------------------------------------------------------
__global__ void k_sums(const float* __restrict__ x, const float* __restrict__ w,
                       float* __restrict__ sum_x, float* __restrict__ sum_w) {
    int i = blockIdx.x * 64 + threadIdx.x;  // 0..1023
    if (i < N) {
        double a = 0.0;
        #pragma unroll 8
        for (int b = 0; b < B; ++b) a += (double)x[b * N + i];
        sum_x[i] = (float)a;
    } else {
        int m = i - N;
        double a = 0.0;
        #pragma unroll 8
        for (int n = 0; n < N; ++n) a += (double)w[n * M + m];
        sum_w[m] = (float)a;
    }
}

// ---------------------------------------------------------------------------
// K2: rel_x[n,m] = sum_b min(x[b,n], t[b,m]) / sum_x[n]
// block (64,4): 64 m-lanes x 4 n-groups; each thread owns 4 consecutive n.
// t[b, m-tile] coalesced; x[b, n0..n0+3] wave-uniform (s_load_dwordx4).
// grid (M/64, N/16) = (8, 32)
// ---------------------------------------------------------------------------
__global__ void k_relx(const float* __restrict__ x, const float* __restrict__ t,
                       const float* __restrict__ sum_x, float* __restrict__ rel_x) {
    const int m  = blockIdx.x * 64 + threadIdx.x;
    const int n0 = blockIdx.y * 16 + threadIdx.y * 4;
    double a0 = 0.0, a1 = 0.0, a2 = 0.0, a3 = 0.0;
    #pragma unroll 4
    for (int b = 0; b < B; ++b) {
        float tb = t[b * M + m];
        const float* xr = x + b * N + n0;
        a0 += (double)fminf(xr[0], tb);
        a1 += (double)fminf(xr[1], tb);
        a2 += (double)fminf(xr[2], tb);
        a3 += (double)fminf(xr[3], tb);
    }
    rel_x[(n0 + 0) * M + m] = (float)a0 / sum_x[n0 + 0];
    rel_x[(n0 + 1) * M + m] = (float)a1 / sum_x[n0 + 1];
    rel_x[(n0 + 2) * M + m] = (float)a2 / sum_x[n0 + 2];
    rel_x[(n0 + 3) * M + m] = (float)a3 / sum_x[n0 + 3];
}

// ---------------------------------------------------------------------------
// K3: per (b,m):
//   pass1 over n: rel_w accum (f64) + ind_w = argmax_n min(x[b,n], rel_x[n,m])
//   rel_w = (float)sum / sum_w[m]
//   ind_x = first n with w[n,m] >= rel_w (== argmax_n min(rel_w, w[n,m]),
//           first-occurrence semantics); fallback: first-occurrence argmax of w col.
//   out: chosen_x = min(x[b,ind_x], w[ind_x,m]); chosen_w likewise with ind_w.
// block (64,4): 64 m-lanes x 4 b; grid (M/64, B/4) = (8, 64)
// ---------------------------------------------------------------------------
__global__ void k_main(const float* __restrict__ x, const float* __restrict__ w,
                       const float* __restrict__ t, const float* __restrict__ rel_x,
                       const float* __restrict__ sum_w, float* __restrict__ out) {
    const int m = blockIdx.x * 64 + threadIdx.x;
    const int b = blockIdx.y * 4 + threadIdx.y;
    const float tbm = t[b * M + m];
    const float* xb = x + b * N;

    double rw_acc = 0.0;
    float best1 = -1e30f;
    int ind_w = 0;
    #pragma unroll 4
    for (int n = 0; n < N; ++n) {
        float wn = w[n * M + m];
        float rx = rel_x[n * M + m];
        rw_acc += (double)fminf(wn, tbm);
        float v = fminf(xb[n], rx);
        if (v > best1) { best1 = v; ind_w = n; }
    }
    float c = (float)rw_acc / sum_w[m];

    // ind_x: first n with w[n,m] >= c; expected ~few iters (early exit).
    int ind_x = -1;
    for (int n = 0; n < N; ++n) {
        if (w[n * M + m] >= c) { ind_x = n; break; }
    }
    if (ind_x < 0) {  // all w[:,m] < c: argmax of column, first occurrence
        float bw = -1e30f; ind_x = 0;
        for (int n = 0; n < N; ++n) {
            float wn = w[n * M + m];
            if (wn > bw) { bw = wn; ind_x = n; }
        }
    }

    out[b * M + m]         = fminf(xb[ind_x], w[ind_x * M + m]);  // chosen_x
    out[B * M + b * M + m] = fminf(xb[ind_w], w[ind_w * M + m]);  // chosen_w
}

extern "C" void kernel_launch(void* const* d_in, const int* in_sizes, int n_in,
                              void* d_out, int out_size, void* d_ws, size_t ws_size,
                              hipStream_t stream) {
    const float* x = (const float*)d_in[0];  // (B, N)
    const float* w = (const float*)d_in[1];  // (N, M)
    const float* t = (const float*)d_in[2];  // (B, M)
    float* out = (float*)d_out;              // chosen_x (B,M) then chosen_w (B,M)

    float* sum_x = (float*)d_ws;             // N floats
    float* sum_w = sum_x + N;                // M floats
    float* rel_x = sum_w + M;                // N*M floats

    k_sums<<<dim3(16), dim3(64), 0, stream>>>(x, w, sum_x, sum_w);
    k_relx<<<dim3(M / 64, N / 16), dim3(64, 4), 0, stream>>>(x, t, sum_x, rel_x);
    k_main<<<dim3(M / 64, B / 4), dim3(64, 4), 0, stream>>>(x, w, t, rel_x, sum_w, out);
}

// Round 2
// 217.049 us; speedup vs baseline: 1.1637x; 1.1637x over previous
//
#include <hip/hip_runtime.h>

#define B 256
#define N 512
#define M 512

// ---------------------------------------------------------------------------
// K1: sum_x[n] = sum_b x[b,n]; sum_w[m] = sum_n w[n,m]. f64 accumulate.
// ---------------------------------------------------------------------------
__global__ void k_sums(const float* __restrict__ x, const float* __restrict__ w,
                       float* __restrict__ sum_x, float* __restrict__ sum_w) {
    int i = blockIdx.x * 64 + threadIdx.x;  // 0..1023
    if (i < N) {
        double a0 = 0.0, a1 = 0.0, a2 = 0.0, a3 = 0.0;
        for (int b = 0; b < B; b += 4) {
            a0 += (double)x[(b + 0) * N + i];
            a1 += (double)x[(b + 1) * N + i];
            a2 += (double)x[(b + 2) * N + i];
            a3 += (double)x[(b + 3) * N + i];
        }
        sum_x[i] = (float)((a0 + a1) + (a2 + a3));
    } else {
        int m = i - N;
        double a0 = 0.0, a1 = 0.0, a2 = 0.0, a3 = 0.0;
        for (int n = 0; n < N; n += 4) {
            a0 += (double)w[(n + 0) * M + m];
            a1 += (double)w[(n + 1) * M + m];
            a2 += (double)w[(n + 2) * M + m];
            a3 += (double)w[(n + 3) * M + m];
        }
        sum_w[m] = (float)((a0 + a1) + (a2 + a3));
    }
}

// ---------------------------------------------------------------------------
// K2: rel_x[n,m] = sum_b min(x[b,n], t[b,m]) / sum_x[n]
// 1 thread per (n,m). block (64,4): lanes=m (coalesced t), ty=n (uniform x).
// grid (M/64, N/4) = (8,128) -> 4096 waves = 16/CU. 8 independent f64 chains.
// ---------------------------------------------------------------------------
__global__ void k_relx(const float* __restrict__ x, const float* __restrict__ t,
                       const float* __restrict__ sum_x, float* __restrict__ rel_x) {
    const int m = blockIdx.x * 64 + threadIdx.x;
    const int n = blockIdx.y * 4 + threadIdx.y;
    const float* xc = x + n;  // x[b,n] = xc[b*N], wave-uniform
    const float* tc = t + m;  // t[b,m] = tc[b*M], coalesced
    double a0 = 0, a1 = 0, a2 = 0, a3 = 0, a4 = 0, a5 = 0, a6 = 0, a7 = 0;
    for (int b = 0; b < B; b += 8) {
        a0 += (double)fminf(xc[(b + 0) * N], tc[(b + 0) * M]);
        a1 += (double)fminf(xc[(b + 1) * N], tc[(b + 1) * M]);
        a2 += (double)fminf(xc[(b + 2) * N], tc[(b + 2) * M]);
        a3 += (double)fminf(xc[(b + 3) * N], tc[(b + 3) * M]);
        a4 += (double)fminf(xc[(b + 4) * N], tc[(b + 4) * M]);
        a5 += (double)fminf(xc[(b + 5) * N], tc[(b + 5) * M]);
        a6 += (double)fminf(xc[(b + 6) * N], tc[(b + 6) * M]);
        a7 += (double)fminf(xc[(b + 7) * N], tc[(b + 7) * M]);
    }
    double s = ((a0 + a1) + (a2 + a3)) + ((a4 + a5) + (a6 + a7));
    rel_x[n * M + m] = (float)s / sum_x[n];
}

// ---------------------------------------------------------------------------
// K3: block = (b, 64-wide m-tile); ty = n-quarter (128 n each).
// pass1: per-quarter argmax of min(x[b,n], rel_x[n,m]) (4 ILP slots,
//        idx tie-break => exact first-occurrence) + f64 partial of
//        sum_n min(w[n,m], t[b,m]).
// combine in LDS (quarters ascending, strict > keeps earliest index).
// then ind_x early-exit scan + outputs (ty==0 waves only).
// grid (M/64, B) = (8,256) = 2048 blocks x 4 waves = 8192 waves (100% occ).
// ---------------------------------------------------------------------------
__global__ __launch_bounds__(256, 8) void k_main(
        const float* __restrict__ x, const float* __restrict__ w,
        const float* __restrict__ t, const float* __restrict__ rel_x,
        const float* __restrict__ sum_w, float* __restrict__ out) {
    const int lane = threadIdx.x;            // m within tile
    const int q    = threadIdx.y;            // n-quarter
    const int m    = blockIdx.x * 64 + lane;
    const int b    = blockIdx.y;
    const float tbm = t[b * M + m];
    const float* xb = x + b * N;
    const float* wc = w + m;                 // w[n,m] = wc[n*M]
    const float* rc = rel_x + m;             // rel_x[n,m] = rc[n*M]

    const int n0 = q * 128;
    float bv0 = -1e30f, bv1 = -1e30f, bv2 = -1e30f, bv3 = -1e30f;
    int   bi0 = 0, bi1 = 0, bi2 = 0, bi3 = 0;
    double rw0 = 0.0, rw1 = 0.0;
    for (int i = 0; i < 128; i += 4) {
        const int n = n0 + i;
        float w0 = wc[(n + 0) * M], w1 = wc[(n + 1) * M];
        float w2 = wc[(n + 2) * M], w3 = wc[(n + 3) * M];
        float r0 = rc[(n + 0) * M], r1 = rc[(n + 1) * M];
        float r2 = rc[(n + 2) * M], r3 = rc[(n + 3) * M];
        float x0 = xb[n + 0], x1 = xb[n + 1], x2 = xb[n + 2], x3 = xb[n + 3];
        rw0 += (double)fminf(w0, tbm) + (double)fminf(w1, tbm);
        rw1 += (double)fminf(w2, tbm) + (double)fminf(w3, tbm);
        float v0 = fminf(x0, r0); if (v0 > bv0) { bv0 = v0; bi0 = n + 0; }
        float v1 = fminf(x1, r1); if (v1 > bv1) { bv1 = v1; bi1 = n + 1; }
        float v2 = fminf(x2, r2); if (v2 > bv2) { bv2 = v2; bi2 = n + 2; }
        float v3 = fminf(x3, r3); if (v3 > bv3) { bv3 = v3; bi3 = n + 3; }
    }
    // merge 4 ILP slots: strictly greater, or equal with smaller index
    float bv = bv0; int bi = bi0;
    if (bv1 > bv || (bv1 == bv && bi1 < bi)) { bv = bv1; bi = bi1; }
    if (bv2 > bv || (bv2 == bv && bi2 < bi)) { bv = bv2; bi = bi2; }
    if (bv3 > bv || (bv3 == bv && bi3 < bi)) { bv = bv3; bi = bi3; }

    __shared__ float  s_val[4][64];
    __shared__ int    s_idx[4][64];
    __shared__ double s_rw[4][64];
    s_val[q][lane] = bv;
    s_idx[q][lane] = bi;
    s_rw[q][lane]  = rw0 + rw1;
    __syncthreads();

    if (q == 0) {
        float v = s_val[0][lane]; int ind_w = s_idx[0][lane];
        #pragma unroll
        for (int k = 1; k < 4; ++k) {
            float vk = s_val[k][lane];
            if (vk > v) { v = vk; ind_w = s_idx[k][lane]; }  // ascending quarters: > keeps earliest
        }
        double rw = (s_rw[0][lane] + s_rw[1][lane]) + (s_rw[2][lane] + s_rw[3][lane]);
        float c = (float)rw / sum_w[m];

        // ind_x: first n with w[n,m] >= c (== first-occurrence argmax of min(c, w))
        int ind_x = -1;
        for (int n = 0; n < N; ++n) {
            if (wc[n * M] >= c) { ind_x = n; break; }
        }
        if (ind_x < 0) {  // all w[:,m] < c: first-occurrence argmax of the column
            float bw = -1e30f; ind_x = 0;
            for (int n = 0; n < N; ++n) {
                float wn = wc[n * M];
                if (wn > bw) { bw = wn; ind_x = n; }
            }
        }
        out[b * M + m]         = fminf(xb[ind_x], wc[ind_x * M]);  // chosen_x
        out[B * M + b * M + m] = fminf(xb[ind_w], wc[ind_w * M]);  // chosen_w
    }
}

extern "C" void kernel_launch(void* const* d_in, const int* in_sizes, int n_in,
                              void* d_out, int out_size, void* d_ws, size_t ws_size,
                              hipStream_t stream) {
    const float* x = (const float*)d_in[0];  // (B, N)
    const float* w = (const float*)d_in[1];  // (N, M)
    const float* t = (const float*)d_in[2];  // (B, M)
    float* out = (float*)d_out;              // chosen_x (B,M) then chosen_w (B,M)

    float* sum_x = (float*)d_ws;             // N floats
    float* sum_w = sum_x + N;                // M floats
    float* rel_x = sum_w + M;                // N*M floats

    k_sums<<<dim3(16), dim3(64), 0, stream>>>(x, w, sum_x, sum_w);
    k_relx<<<dim3(M / 64, N / 4), dim3(64, 4), 0, stream>>>(x, t, sum_x, rel_x);
    k_main<<<dim3(M / 64, B), dim3(64, 4), 0, stream>>>(x, w, t, rel_x, sum_w, out);
}

// Round 3
// 174.318 us; speedup vs baseline: 1.4489x; 1.2451x over previous
//
#include <hip/hip_runtime.h>

#define B 256
#define N 512
#define M 512

// ---------------------------------------------------------------------------
// K1: sum_x[n] = sum_b x[b,n]; sum_w[m] = sum_n w[n,m]. f64 accumulate.
// ---------------------------------------------------------------------------
__global__ void k_sums(const float* __restrict__ x, const float* __restrict__ w,
                       float* __restrict__ sum_x, float* __restrict__ sum_w) {
    int i = blockIdx.x * 64 + threadIdx.x;  // 0..1023
    if (i < N) {
        double a0 = 0.0, a1 = 0.0, a2 = 0.0, a3 = 0.0;
        for (int b = 0; b < B; b += 4) {
            a0 += (double)x[(b + 0) * N + i];
            a1 += (double)x[(b + 1) * N + i];
            a2 += (double)x[(b + 2) * N + i];
            a3 += (double)x[(b + 3) * N + i];
        }
        sum_x[i] = (float)((a0 + a1) + (a2 + a3));
    } else {
        int m = i - N;
        double a0 = 0.0, a1 = 0.0, a2 = 0.0, a3 = 0.0;
        for (int n = 0; n < N; n += 4) {
            a0 += (double)w[(n + 0) * M + m];
            a1 += (double)w[(n + 1) * M + m];
            a2 += (double)w[(n + 2) * M + m];
            a3 += (double)w[(n + 3) * M + m];
        }
        sum_w[m] = (float)((a0 + a1) + (a2 + a3));
    }
}

// ---------------------------------------------------------------------------
// K2: rel_x[n,m] = sum_b min(x[b,n], t[b,m]) / sum_x[n]
// Tile: 8 n x 64 m per block. x[0:256, n-tile] staged in LDS ONCE (8 KB),
// then the b-loop reads only t (coalesced 256B/wave) + LDS broadcasts.
// block (64,4): lanes=m, q owns n = n0+q*2 .. +1 (2 n, 4 f64 ILP chains).
// grid (M/64, N/8) = (8,64) = 512 blocks = 2048 waves = 2/SIMD.
// ---------------------------------------------------------------------------
__global__ __launch_bounds__(256) void k_relx(
        const float* __restrict__ x, const float* __restrict__ t,
        const float* __restrict__ sum_x, float* __restrict__ rel_x) {
    const int lane = threadIdx.x, q = threadIdx.y;
    const int m  = blockIdx.x * 64 + lane;
    const int n0 = blockIdx.y * 8;
    __shared__ float s_x[B][8];          // s_x[b][n-n0]
    {
        int tid = q * 64 + lane;         // 0..255 == b row to stage
        const float4* xr = (const float4*)(x + tid * N + n0);
        float4 v0 = xr[0], v1 = xr[1];
        *(float4*)&s_x[tid][0] = v0;
        *(float4*)&s_x[tid][4] = v1;
    }
    __syncthreads();
    const int n = n0 + q * 2;
    const float* tc = t + m;             // t[b,m] = tc[b*M], coalesced
    double a0 = 0.0, a1 = 0.0, b0 = 0.0, b1 = 0.0;
    #pragma unroll 4
    for (int b = 0; b < B; b += 2) {
        float t0 = tc[b * M], t1 = tc[(b + 1) * M];
        float2 x0 = *(const float2*)&s_x[b][q * 2];      // uniform -> broadcast
        float2 x1 = *(const float2*)&s_x[b + 1][q * 2];
        a0 += (double)fminf(x0.x, t0);
        a1 += (double)fminf(x0.y, t0);
        b0 += (double)fminf(x1.x, t1);
        b1 += (double)fminf(x1.y, t1);
    }
    rel_x[n * M + m]       = (float)(a0 + b0) / sum_x[n];
    rel_x[(n + 1) * M + m] = (float)(a1 + b1) / sum_x[n + 1];
}

// ---------------------------------------------------------------------------
// K3a: per (b,m): rel_w = (sum_n min(w[n,m], t[b,m])) / sum_w[m]  (f64),
//      ind_x = first n with w[n,m] >= rel_w  (== first-occurrence argmax of
//      min(rel_w, w[n,m])); early-exit chunked scan (expected ~2 rounds);
//      cold fallback = first-occurrence column argmax.  chosen_x written.
// block (64,4): lanes=m, q=b. grid (8, B/4=64) = 512 blocks = 2/SIMD.
// ---------------------------------------------------------------------------
__global__ __launch_bounds__(256) void k_rw_scan(
        const float* __restrict__ x, const float* __restrict__ w,
        const float* __restrict__ t, const float* __restrict__ sum_w,
        float* __restrict__ out) {
    const int m = blockIdx.x * 64 + threadIdx.x;
    const int b = blockIdx.y * 4 + threadIdx.y;
    const float tbm = t[b * M + m];
    const float* wc = w + m;             // w[n,m] = wc[n*M]
    double accA = 0.0, accB = 0.0;
    #pragma unroll 4
    for (int n = 0; n < N; n += 2) {     // 8 loads in flight per body
        float w0 = wc[n * M], w1 = wc[(n + 1) * M];
        accA += (double)fminf(w0, tbm);
        accB += (double)fminf(w1, tbm);
    }
    float c = (float)(accA + accB) / sum_w[m];

    int ind = -1;
    for (int n0 = 0; n0 < N; n0 += 8) {
        float wv[8];
        #pragma unroll
        for (int j = 0; j < 8; ++j) wv[j] = wc[(n0 + j) * M];
        #pragma unroll
        for (int j = 0; j < 8; ++j)
            if (ind < 0 && wv[j] >= c) ind = n0 + j;
        if (__ballot(ind >= 0) == ~0ULL) break;
    }
    if (ind < 0) {                       // all w[:,m] < c: first-occurrence argmax
        float bw = -1e30f; ind = 0;
        for (int n = 0; n < N; ++n) {
            float wn = wc[n * M];
            if (wn > bw) { bw = wn; ind = n; }
        }
    }
    out[b * M + m] = fminf(x[b * N + ind], wc[ind * M]);   // chosen_x
}

// ---------------------------------------------------------------------------
// K3b: ind_w[b,m] = first-occurrence argmax_n min(x[b,n], rel_x[n,m]);
//      chosen_w written.  4 b per block share each rel_x column read.
// x[b0:b0+4, :] staged TRANSPOSED in LDS (s_xt[n][j], 8 KB) -> per n one
// uniform ds_read_b128 gives all 4 b's x-value.
// block (64,4): lanes=m, q=n-quarter (128 n). LDS combine (quarters
// ascending, strict > keeps earliest index). grid (8, B/4=64) = 2/SIMD.
// ---------------------------------------------------------------------------
__global__ __launch_bounds__(256) void k_argmax(
        const float* __restrict__ x, const float* __restrict__ w,
        const float* __restrict__ rel_x, float* __restrict__ out) {
    const int lane = threadIdx.x, q = threadIdx.y;
    const int m  = blockIdx.x * 64 + lane;
    const int b0 = blockIdx.y * 4;
    __shared__ float s_xt[N][4];         // s_xt[n][j] = x[b0+j][n]
    {
        int tid = q * 64 + lane;         // 0..255
        int n = tid * 2;
        #pragma unroll
        for (int j = 0; j < 4; ++j) {
            float2 v = *(const float2*)(x + (b0 + j) * N + n);
            s_xt[n][j]     = v.x;
            s_xt[n + 1][j] = v.y;
        }
    }
    __syncthreads();
    const float* rc = rel_x + m;         // rel_x[n,m] = rc[n*M]
    float bv0 = -1e30f, bv1 = -1e30f, bv2 = -1e30f, bv3 = -1e30f;
    int   bi0 = 0, bi1 = 0, bi2 = 0, bi3 = 0;
    const int nq = q * 128;
    #pragma unroll 4
    for (int i = 0; i < 128; ++i) {
        const int n = nq + i;
        float rv = rc[n * M];
        float4 xv = *(const float4*)&s_xt[n][0];   // uniform -> broadcast
        float v0 = fminf(xv.x, rv); if (v0 > bv0) { bv0 = v0; bi0 = n; }
        float v1 = fminf(xv.y, rv); if (v1 > bv1) { bv1 = v1; bi1 = n; }
        float v2 = fminf(xv.z, rv); if (v2 > bv2) { bv2 = v2; bi2 = n; }
        float v3 = fminf(xv.w, rv); if (v3 > bv3) { bv3 = v3; bi3 = n; }
    }
    __shared__ float s_v[4][4][64];      // [quarter][b-slot][lane]
    __shared__ int   s_i[4][4][64];
    s_v[q][0][lane] = bv0; s_i[q][0][lane] = bi0;
    s_v[q][1][lane] = bv1; s_i[q][1][lane] = bi1;
    s_v[q][2][lane] = bv2; s_i[q][2][lane] = bi2;
    s_v[q][3][lane] = bv3; s_i[q][3][lane] = bi3;
    __syncthreads();
    {
        const int j = q;                 // each wave finalizes one b
        float v = s_v[0][j][lane]; int ind = s_i[0][j][lane];
        #pragma unroll
        for (int k = 1; k < 4; ++k) {    // quarters ascending: > keeps earliest
            float vk = s_v[k][j][lane];
            if (vk > v) { v = vk; ind = s_i[k][j][lane]; }
        }
        const int bb = b0 + j;
        out[B * M + bb * M + m] = fminf(s_xt[ind][j], w[ind * M + m]);  // chosen_w
    }
}

extern "C" void kernel_launch(void* const* d_in, const int* in_sizes, int n_in,
                              void* d_out, int out_size, void* d_ws, size_t ws_size,
                              hipStream_t stream) {
    const float* x = (const float*)d_in[0];  // (B, N)
    const float* w = (const float*)d_in[1];  // (N, M)
    const float* t = (const float*)d_in[2];  // (B, M)
    float* out = (float*)d_out;              // chosen_x (B,M) then chosen_w (B,M)

    float* sum_x = (float*)d_ws;             // N floats
    float* sum_w = sum_x + N;                // M floats
    float* rel_x = sum_w + M;                // N*M floats

    k_sums<<<dim3(16), dim3(64), 0, stream>>>(x, w, sum_x, sum_w);
    k_relx<<<dim3(M / 64, N / 8), dim3(64, 4), 0, stream>>>(x, t, sum_x, rel_x);
    k_rw_scan<<<dim3(M / 64, B / 4), dim3(64, 4), 0, stream>>>(x, w, t, sum_w, out);
    k_argmax<<<dim3(M / 64, B / 4), dim3(64, 4), 0, stream>>>(x, w, rel_x, out);
}

// Round 4
// 168.594 us; speedup vs baseline: 1.4981x; 1.0339x over previous
//
#include <hip/hip_runtime.h>

#define B 256
#define N 512
#define M 512
#define BM (B * M)   // 131072
#define NM (N * M)   // 262144

// ---------------------------------------------------------------------------
// k_xt: xT[n][b] = x[b][n].  64x64 tiles through padded LDS.
// grid (N/64, B/64) = (8,4), block (64,4).
// ---------------------------------------------------------------------------
__global__ __launch_bounds__(256) void k_xt(const float* __restrict__ x,
                                            float* __restrict__ xT) {
    __shared__ float s[64][65];
    const int tx = threadIdx.x, ty = threadIdx.y;
    const int n0 = blockIdx.x * 64, b0 = blockIdx.y * 64;
    #pragma unroll
    for (int j = 0; j < 16; ++j) {
        int bl = ty * 16 + j;
        s[bl][tx] = x[(b0 + bl) * N + n0 + tx];
    }
    __syncthreads();
    #pragma unroll
    for (int j = 0; j < 16; ++j) {
        int nl = ty * 16 + j;
        xT[(n0 + nl) * B + b0 + tx] = s[tx][nl];
    }
}

// ---------------------------------------------------------------------------
// k_sums: sum_x[n] = sum_b x[b,n]; sum_w[m] = sum_n w[n,m]. f64, fixed order.
// ---------------------------------------------------------------------------
__global__ void k_sums(const float* __restrict__ x, const float* __restrict__ w,
                       float* __restrict__ sum_x, float* __restrict__ sum_w) {
    int i = blockIdx.x * 64 + threadIdx.x;  // 0..1023
    if (i < N) {
        double a0 = 0.0, a1 = 0.0, a2 = 0.0, a3 = 0.0;
        for (int b = 0; b < B; b += 4) {
            a0 += (double)x[(b + 0) * N + i];
            a1 += (double)x[(b + 1) * N + i];
            a2 += (double)x[(b + 2) * N + i];
            a3 += (double)x[(b + 3) * N + i];
        }
        sum_x[i] = (float)((a0 + a1) + (a2 + a3));
    } else {
        int m = i - N;
        double a0 = 0.0, a1 = 0.0, a2 = 0.0, a3 = 0.0;
        for (int n = 0; n < N; n += 4) {
            a0 += (double)w[(n + 0) * M + m];
            a1 += (double)w[(n + 1) * M + m];
            a2 += (double)w[(n + 2) * M + m];
            a3 += (double)w[(n + 3) * M + m];
        }
        sum_w[m] = (float)((a0 + a1) + (a2 + a3));
    }
}

// ---------------------------------------------------------------------------
// k_relxA: px[chunk][n,m] = sum_{b in chunk(128)} min(x[b,n], t[b,m]). f32.
// Tile 32n x 32m; block (16,16) -> 2n x 2m per thread; LDS sub-chunks of 32 b.
// grid (M/32, N/32, 2) = 512 blocks = 2/CU, 2 waves/SIMD.
// ---------------------------------------------------------------------------
__global__ __launch_bounds__(256) void k_relxA(const float* __restrict__ xT,
                                               const float* __restrict__ t,
                                               float* __restrict__ px) {
    const int tx = threadIdx.x, ty = threadIdx.y;
    const int m0 = blockIdx.x * 32, n0 = blockIdx.y * 32;
    const int bbase = blockIdx.z * 128;
    __shared__ float s_t[32][32];    // [b-local][m-local]
    __shared__ float s_xn[32][36];   // [n-local][b-local], pad 36 (16B-aligned rows)
    const int tid = ty * 16 + tx;
    const int sr = tid / 8, sc4 = (tid & 7) * 4;
    const int nA = ty * 2, nB = nA + 1;
    float a00 = 0.f, a01 = 0.f, a10 = 0.f, a11 = 0.f;
    for (int scnk = 0; scnk < 4; ++scnk) {
        const int bb = bbase + scnk * 32;
        __syncthreads();
        *(float4*)&s_t[sr][sc4]  = *(const float4*)&t[(bb + sr) * M + m0 + sc4];
        *(float4*)&s_xn[sr][sc4] = *(const float4*)&xT[(n0 + sr) * B + bb + sc4];
        __syncthreads();
        #pragma unroll 4
        for (int i = 0; i < 32; ++i) {
            float2 tv = *(const float2*)&s_t[i][tx * 2];
            float x0 = s_xn[nA][i];
            float x1 = s_xn[nB][i];
            a00 += fminf(x0, tv.x); a01 += fminf(x0, tv.y);
            a10 += fminf(x1, tv.x); a11 += fminf(x1, tv.y);
        }
    }
    const int base = blockIdx.z * NM;
    const int mA = m0 + tx * 2;
    px[base + (n0 + nA) * M + mA]     = a00;
    px[base + (n0 + nA) * M + mA + 1] = a01;
    px[base + (n0 + nB) * M + mA]     = a10;
    px[base + (n0 + nB) * M + mA + 1] = a11;
}

// ---------------------------------------------------------------------------
// k_relxB: rel_x[n,m] = (px[0]+px[1]) / sum_x[n].  float4, 256 blocks.
// ---------------------------------------------------------------------------
__global__ void k_relxB(const float* __restrict__ px, const float* __restrict__ sum_x,
                        float* __restrict__ rel_x) {
    int e = (blockIdx.x * 256 + threadIdx.x) * 4;
    int n = e >> 9;
    float4 p0 = *(const float4*)&px[e];
    float4 p1 = *(const float4*)&px[NM + e];
    float sx = sum_x[n];
    float4 r;
    r.x = (p0.x + p1.x) / sx;
    r.y = (p0.y + p1.y) / sx;
    r.z = (p0.z + p1.z) / sx;
    r.w = (p0.w + p1.w) / sx;
    *(float4*)&rel_x[e] = r;
}

// ---------------------------------------------------------------------------
// k_bmA: per n-chunk(128): partial f64 rw[b,m] = sum_n min(w[n,m], t[b,m]) and
// partial first-occurrence argmax of min(x[b,n], rel_x[n,m]).
// Tile 32b x 32m; block (16,16) -> 2b x 2m per thread; LDS sub-chunks of 32 n.
// grid (M/32, B/32, 4) = 512 blocks = 2/CU, 2 waves/SIMD.
// ---------------------------------------------------------------------------
__global__ __launch_bounds__(256) void k_bmA(
        const float* __restrict__ w, const float* __restrict__ t,
        const float* __restrict__ xT, const float* __restrict__ rel_x,
        float* __restrict__ pv, int* __restrict__ pi, double* __restrict__ prw) {
    const int tx = threadIdx.x, ty = threadIdx.y;
    const int m0 = blockIdx.x * 32, b0 = blockIdx.y * 32;
    const int nbase = blockIdx.z * 128;
    __shared__ float s_w[32][32];    // [n-local][m-local]
    __shared__ float s_r[32][32];    // [n-local][m-local]
    __shared__ float s_xb[32][32];   // [n-local][b-local]
    const int tid = ty * 16 + tx;
    const int sr = tid / 8, sc4 = (tid & 7) * 4;
    const int mA = m0 + tx * 2, mB = mA + 1;
    const int bA = b0 + ty * 2, bB = bA + 1;
    const float t00 = t[bA * M + mA], t01 = t[bA * M + mB];
    const float t10 = t[bB * M + mA], t11 = t[bB * M + mB];
    double rw00 = 0.0, rw01 = 0.0, rw10 = 0.0, rw11 = 0.0;
    float bv00 = -1.f, bv01 = -1.f, bv10 = -1.f, bv11 = -1.f;
    int   bi00 = 0, bi01 = 0, bi10 = 0, bi11 = 0;
    for (int scnk = 0; scnk < 4; ++scnk) {
        const int nb = nbase + scnk * 32;
        __syncthreads();
        *(float4*)&s_w[sr][sc4]  = *(const float4*)&w[(nb + sr) * M + m0 + sc4];
        *(float4*)&s_r[sr][sc4]  = *(const float4*)&rel_x[(nb + sr) * M + m0 + sc4];
        *(float4*)&s_xb[sr][sc4] = *(const float4*)&xT[(nb + sr) * B + b0 + sc4];
        __syncthreads();
        #pragma unroll 4
        for (int i = 0; i < 32; ++i) {
            const int n = nb + i;
            float2 wv = *(const float2*)&s_w[i][tx * 2];
            float2 rv = *(const float2*)&s_r[i][tx * 2];
            float2 xv = *(const float2*)&s_xb[i][ty * 2];
            rw00 += (double)fminf(wv.x, t00); rw01 += (double)fminf(wv.y, t01);
            rw10 += (double)fminf(wv.x, t10); rw11 += (double)fminf(wv.y, t11);
            float v;
            v = fminf(xv.x, rv.x); if (v > bv00) { bv00 = v; bi00 = n; }
            v = fminf(xv.x, rv.y); if (v > bv01) { bv01 = v; bi01 = n; }
            v = fminf(xv.y, rv.x); if (v > bv10) { bv10 = v; bi10 = n; }
            v = fminf(xv.y, rv.y); if (v > bv11) { bv11 = v; bi11 = n; }
        }
    }
    const int base = blockIdx.z * BM;
    pv[base + bA * M + mA] = bv00; pi[base + bA * M + mA] = bi00; prw[base + bA * M + mA] = rw00;
    pv[base + bA * M + mB] = bv01; pi[base + bA * M + mB] = bi01; prw[base + bA * M + mB] = rw01;
    pv[base + bB * M + mA] = bv10; pi[base + bB * M + mA] = bi10; prw[base + bB * M + mA] = rw10;
    pv[base + bB * M + mB] = bv11; pi[base + bB * M + mB] = bi11; prw[base + bB * M + mB] = rw11;
}

// ---------------------------------------------------------------------------
// k_bmB: combine 4 chunk-partials (ascending, strict > = first occurrence),
// c = f64 rw total / sum_w; early-exit ind_x scan; write both outputs.
// block (64,4), grid (M/64, B/4) = 512 blocks.
// ---------------------------------------------------------------------------
__global__ __launch_bounds__(256) void k_bmB(
        const float* __restrict__ x, const float* __restrict__ w,
        const float* __restrict__ sum_w, const float* __restrict__ pv,
        const int* __restrict__ pi, const double* __restrict__ prw,
        float* __restrict__ out) {
    const int m = blockIdx.x * 64 + threadIdx.x;
    const int b = blockIdx.y * 4 + threadIdx.y;
    const int o = b * M + m;
    float bv = pv[o]; int bi = pi[o];
    {
        float v1 = pv[BM + o], v2 = pv[2 * BM + o], v3 = pv[3 * BM + o];
        int   i1 = pi[BM + o], i2 = pi[2 * BM + o], i3 = pi[3 * BM + o];
        if (v1 > bv) { bv = v1; bi = i1; }
        if (v2 > bv) { bv = v2; bi = i2; }
        if (v3 > bv) { bv = v3; bi = i3; }
    }
    double rwt = (prw[o] + prw[BM + o]) + (prw[2 * BM + o] + prw[3 * BM + o]);
    float c = (float)rwt / sum_w[m];
    const float* wc = w + m;
    int ind = -1;
    for (int n0 = 0; n0 < N; n0 += 8) {
        float wv[8];
        #pragma unroll
        for (int j = 0; j < 8; ++j) wv[j] = wc[(n0 + j) * M];
        #pragma unroll
        for (int j = 0; j < 8; ++j)
            if (ind < 0 && wv[j] >= c) ind = n0 + j;
        if (__ballot(ind >= 0) == ~0ULL) break;
    }
    if (ind < 0) {  // all w[:,m] < c: first-occurrence argmax of the column
        float bw = -1e30f; ind = 0;
        for (int n = 0; n < N; ++n) {
            float wn = wc[n * M];
            if (wn > bw) { bw = wn; ind = n; }
        }
    }
    out[o]      = fminf(x[b * N + ind], wc[ind * M]);  // chosen_x
    out[BM + o] = fminf(x[b * N + bi],  wc[bi * M]);   // chosen_w
}

extern "C" void kernel_launch(void* const* d_in, const int* in_sizes, int n_in,
                              void* d_out, int out_size, void* d_ws, size_t ws_size,
                              hipStream_t stream) {
    const float* x = (const float*)d_in[0];  // (B, N)
    const float* w = (const float*)d_in[1];  // (N, M)
    const float* t = (const float*)d_in[2];  // (B, M)
    float* out = (float*)d_out;

    float* ws = (float*)d_ws;
    // ws layout (float offsets), ~10 MB total:
    float* xT    = ws;                   // 131072
    float* sum_x = ws + 131072;          // 512
    float* sum_w = ws + 131584;          // 512
    float* scr   = ws + 132096;          // scratch region (aliased):
    float*  px   = scr;                  //   relx partials: 2*NM floats
    float*  pv   = scr;                  //   bm partials (after px dead): 4*BM
    int*    pi   = (int*)(scr + 4 * BM); //   4*BM ints
    double* prw  = (double*)(scr + 8 * BM); // 4*BM doubles (8B-aligned offset)
    float* rel_x = scr + 16 * BM;        // NM floats

    k_xt   <<<dim3(N / 64, B / 64), dim3(64, 4),  0, stream>>>(x, xT);
    k_sums <<<dim3(16),             dim3(64),     0, stream>>>(x, w, sum_x, sum_w);
    k_relxA<<<dim3(M / 32, N / 32, 2), dim3(16, 16), 0, stream>>>(xT, t, px);
    k_relxB<<<dim3(NM / 1024),      dim3(256),    0, stream>>>(px, sum_x, rel_x);
    k_bmA  <<<dim3(M / 32, B / 32, 4), dim3(16, 16), 0, stream>>>(w, t, xT, rel_x, pv, pi, prw);
    k_bmB  <<<dim3(M / 64, B / 4),  dim3(64, 4),  0, stream>>>(x, w, sum_w, pv, pi, prw, out);
}

// Round 5
// 124.641 us; speedup vs baseline: 2.0264x; 1.3526x over previous
//
#include <hip/hip_runtime.h>

#define B 256
#define N 512
#define M 512
#define BM (B * M)   // 131072
#define NM (N * M)   // 262144

// ---------------------------------------------------------------------------
// k_xt: xT[n][b] = x[b][n].  64x64 tiles through padded LDS.
// ---------------------------------------------------------------------------
__global__ __launch_bounds__(256) void k_xt(const float* __restrict__ x,
                                            float* __restrict__ xT) {
    __shared__ float s[64][65];
    const int tx = threadIdx.x, ty = threadIdx.y;
    const int n0 = blockIdx.x * 64, b0 = blockIdx.y * 64;
    #pragma unroll
    for (int j = 0; j < 16; ++j) {
        int bl = ty * 16 + j;
        s[bl][tx] = x[(b0 + bl) * N + n0 + tx];
    }
    __syncthreads();
    #pragma unroll
    for (int j = 0; j < 16; ++j) {
        int nl = ty * 16 + j;
        xT[(n0 + nl) * B + b0 + tx] = s[tx][nl];
    }
}

// ---------------------------------------------------------------------------
// k_sums: sum_x[n] = sum_b x[b,n]; sum_w[m] = sum_n w[n,m]. f64, fixed order.
// ---------------------------------------------------------------------------
__global__ void k_sums(const float* __restrict__ x, const float* __restrict__ w,
                       float* __restrict__ sum_x, float* __restrict__ sum_w) {
    int i = blockIdx.x * 64 + threadIdx.x;  // 0..1023
    if (i < N) {
        double a0 = 0.0, a1 = 0.0, a2 = 0.0, a3 = 0.0;
        for (int b = 0; b < B; b += 4) {
            a0 += (double)x[(b + 0) * N + i];
            a1 += (double)x[(b + 1) * N + i];
            a2 += (double)x[(b + 2) * N + i];
            a3 += (double)x[(b + 3) * N + i];
        }
        sum_x[i] = (float)((a0 + a1) + (a2 + a3));
    } else {
        int m = i - N;
        double a0 = 0.0, a1 = 0.0, a2 = 0.0, a3 = 0.0;
        for (int n = 0; n < N; n += 4) {
            a0 += (double)w[(n + 0) * M + m];
            a1 += (double)w[(n + 1) * M + m];
            a2 += (double)w[(n + 2) * M + m];
            a3 += (double)w[(n + 3) * M + m];
        }
        sum_w[m] = (float)((a0 + a1) + (a2 + a3));
    }
}

// ---------------------------------------------------------------------------
// k_sortw: one block per column m.
//  pmT[m][n]  = prefix max of w[0..n, m]          (for ind_x binary search)
//  swT[m][j]  = w[:, m] sorted ascending          (for rel_w CDF)
//  psT[m][k]  = f64 sum of the k smallest values  (k = 0..512, row stride 514)
// ---------------------------------------------------------------------------
__global__ __launch_bounds__(512) void k_sortw(const float* __restrict__ w,
                                               float* __restrict__ pmT,
                                               float* __restrict__ swT,
                                               double* __restrict__ psT) {
    const int m = blockIdx.x, tid = threadIdx.x;
    __shared__ float  s[512];
    __shared__ float  pm[512];
    __shared__ double ps[512];
    float v = w[tid * M + m];
    s[tid] = v;
    pm[tid] = v;
    __syncthreads();
    // inclusive prefix max (Hillis-Steele, read-sync-write-sync)
    for (int off = 1; off < 512; off <<= 1) {
        float cur = pm[tid];
        float oth = (tid >= off) ? pm[tid - off] : -1.0f;
        __syncthreads();
        pm[tid] = fmaxf(cur, oth);
        __syncthreads();
    }
    pmT[m * 512 + tid] = pm[tid];
    // bitonic sort ascending
    for (int k = 2; k <= 512; k <<= 1) {
        for (int j = k >> 1; j > 0; j >>= 1) {
            int ixj = tid ^ j;
            if (ixj > tid) {
                float a = s[tid], b2 = s[ixj];
                bool up = ((tid & k) == 0);
                if ((a > b2) == up) { s[tid] = b2; s[ixj] = a; }
            }
            __syncthreads();
        }
    }
    swT[m * 512 + tid] = s[tid];
    // f64 inclusive prefix sum of sorted values
    ps[tid] = (double)s[tid];
    __syncthreads();
    for (int off = 1; off < 512; off <<= 1) {
        double cur = ps[tid];
        double oth = (tid >= off) ? ps[tid - off] : 0.0;
        __syncthreads();
        ps[tid] = cur + oth;
        __syncthreads();
    }
    if (tid == 0) psT[m * 514] = 0.0;
    psT[m * 514 + tid + 1] = ps[tid];
}

// ---------------------------------------------------------------------------
// k_relxA: px[z][n,m] = sum_{b in chunk z} min(x[b,n], t[b,m]). f32.
// Tile 32n x 32m; block (16,16) -> 2n x 2m per thread; LDS sub-chunks of 32 b.
// grid (16, 16, Zr).
// ---------------------------------------------------------------------------
__global__ __launch_bounds__(256) void k_relxA(const float* __restrict__ xT,
                                               const float* __restrict__ t,
                                               float* __restrict__ px, int nsub) {
    const int tx = threadIdx.x, ty = threadIdx.y;
    const int m0 = blockIdx.x * 32, n0 = blockIdx.y * 32;
    const int bbase = blockIdx.z * (nsub * 32);
    __shared__ float s_t[32][32];    // [b-local][m-local]
    __shared__ float s_xn[32][36];   // [n-local][b-local], pad 36 breaks conflicts
    const int tid = ty * 16 + tx;
    const int sr = tid / 8, sc4 = (tid & 7) * 4;
    const int nA = ty * 2, nB = nA + 1;
    float a00 = 0.f, a01 = 0.f, a10 = 0.f, a11 = 0.f;
    for (int scnk = 0; scnk < nsub; ++scnk) {
        const int bb = bbase + scnk * 32;
        __syncthreads();
        *(float4*)&s_t[sr][sc4]  = *(const float4*)&t[(bb + sr) * M + m0 + sc4];
        *(float4*)&s_xn[sr][sc4] = *(const float4*)&xT[(n0 + sr) * B + bb + sc4];
        __syncthreads();
        #pragma unroll 8
        for (int i = 0; i < 32; ++i) {
            float2 tv = *(const float2*)&s_t[i][tx * 2];
            float x0 = s_xn[nA][i];
            float x1 = s_xn[nB][i];
            a00 += fminf(x0, tv.x); a01 += fminf(x0, tv.y);
            a10 += fminf(x1, tv.x); a11 += fminf(x1, tv.y);
        }
    }
    const int base = blockIdx.z * NM;
    const int mA = m0 + tx * 2;
    px[base + (n0 + nA) * M + mA]     = a00;
    px[base + (n0 + nA) * M + mA + 1] = a01;
    px[base + (n0 + nB) * M + mA]     = a10;
    px[base + (n0 + nB) * M + mA + 1] = a11;
}

// ---------------------------------------------------------------------------
// k_relxB: rel_x[n,m] = (sum_z px[z]) / sum_x[n].
// ---------------------------------------------------------------------------
__global__ void k_relxB(const float* __restrict__ px, const float* __restrict__ sum_x,
                        float* __restrict__ rel_x, int Zr) {
    int e = (blockIdx.x * 256 + threadIdx.x) * 4;
    int n = e >> 9;
    float4 r = *(const float4*)&px[e];
    for (int z = 1; z < Zr; ++z) {
        float4 p = *(const float4*)&px[z * NM + e];
        r.x += p.x; r.y += p.y; r.z += p.z; r.w += p.w;
    }
    float sx = sum_x[n];
    r.x /= sx; r.y /= sx; r.z /= sx; r.w /= sx;
    *(float4*)&rel_x[e] = r;
}

// ---------------------------------------------------------------------------
// k_bmA2: pure f32 argmax partials over n-chunks:
//   pv/pi[z][b,m] = first-occurrence argmax_{n in chunk z} min(x[b,n], rel_x[n,m])
// Tile 32b x 32m; block (16,16) -> 2b x 2m per thread; grid (16, 8, Zb).
// ---------------------------------------------------------------------------
__global__ __launch_bounds__(256) void k_bmA2(const float* __restrict__ xT,
                                              const float* __restrict__ rel_x,
                                              float* __restrict__ pv,
                                              unsigned short* __restrict__ pi, int nsub) {
    const int tx = threadIdx.x, ty = threadIdx.y;
    const int m0 = blockIdx.x * 32, b0 = blockIdx.y * 32;
    const int nbase = blockIdx.z * (nsub * 32);
    __shared__ float s_r[32][32];    // [n-local][m-local]
    __shared__ float s_xb[32][32];   // [n-local][b-local]
    const int tid = ty * 16 + tx;
    const int sr = tid / 8, sc4 = (tid & 7) * 4;
    float bv00 = -1.f, bv01 = -1.f, bv10 = -1.f, bv11 = -1.f;
    int   bi00 = 0, bi01 = 0, bi10 = 0, bi11 = 0;
    for (int scnk = 0; scnk < nsub; ++scnk) {
        const int nb = nbase + scnk * 32;
        __syncthreads();
        *(float4*)&s_r[sr][sc4]  = *(const float4*)&rel_x[(nb + sr) * M + m0 + sc4];
        *(float4*)&s_xb[sr][sc4] = *(const float4*)&xT[(nb + sr) * B + b0 + sc4];
        __syncthreads();
        #pragma unroll 8
        for (int i = 0; i < 32; ++i) {
            const int n = nb + i;
            float2 rv = *(const float2*)&s_r[i][tx * 2];
            float2 xv = *(const float2*)&s_xb[i][ty * 2];
            float v;
            v = fminf(xv.x, rv.x); if (v > bv00) { bv00 = v; bi00 = n; }
            v = fminf(xv.x, rv.y); if (v > bv01) { bv01 = v; bi01 = n; }
            v = fminf(xv.y, rv.x); if (v > bv10) { bv10 = v; bi10 = n; }
            v = fminf(xv.y, rv.y); if (v > bv11) { bv11 = v; bi11 = n; }
        }
    }
    const int base = blockIdx.z * BM;
    const int mA = m0 + tx * 2, bA = b0 + ty * 2;
    pv[base + bA * M + mA]           = bv00; pi[base + bA * M + mA]           = (unsigned short)bi00;
    pv[base + bA * M + mA + 1]       = bv01; pi[base + bA * M + mA + 1]       = (unsigned short)bi01;
    pv[base + (bA + 1) * M + mA]     = bv10; pi[base + (bA + 1) * M + mA]     = (unsigned short)bi10;
    pv[base + (bA + 1) * M + mA + 1] = bv11; pi[base + (bA + 1) * M + mA + 1] = (unsigned short)bi11;
}

// ---------------------------------------------------------------------------
// k_bmB: per (b,m):
//   merge argmax partials (ascending z, strict > = first occurrence) -> ind_w
//   k = lower_bound(swT[m], t)  -> rw = psT[m][k] + t*(512-k)  (f64 exact)
//   c = (float)rw / sum_w[m]
//   ind_x = lower_bound(pmT[m], min(c, colmax))   (== first n with w>=c, or
//           first-occurrence column argmax when c > colmax)
//   write chosen_x, chosen_w.
// ---------------------------------------------------------------------------
__global__ __launch_bounds__(256) void k_bmB(
        const float* __restrict__ x, const float* __restrict__ w,
        const float* __restrict__ t, const float* __restrict__ sum_w,
        const float* __restrict__ swT, const float* __restrict__ pmT,
        const double* __restrict__ psT, const float* __restrict__ pv,
        const unsigned short* __restrict__ pi, float* __restrict__ out, int Zb) {
    const int m = blockIdx.x * 64 + threadIdx.x;
    const int b = blockIdx.y * 4 + threadIdx.y;
    const int o = b * M + m;
    float bv = pv[o]; int bi = pi[o];
    for (int z = 1; z < Zb; ++z) {
        float v = pv[z * BM + o];
        if (v > bv) { bv = v; bi = pi[z * BM + o]; }
    }
    const float tbm = t[o];
    const float* sw = swT + m * 512;
    int lo = 0, hi = 512;
    while (lo < hi) { int mid = (lo + hi) >> 1; if (sw[mid] >= tbm) hi = mid; else lo = mid + 1; }
    const int kk = lo;
    double rw = psT[m * 514 + kk] + (double)tbm * (double)(512 - kk);
    float c = (float)rw / sum_w[m];

    const float* pm = pmT + m * 512;
    float tgt = fminf(c, pm[511]);
    lo = 0; hi = 511;
    while (lo < hi) { int mid = (lo + hi) >> 1; if (pm[mid] >= tgt) hi = mid; else lo = mid + 1; }
    const int ind = lo;

    out[o]      = fminf(x[b * N + ind], w[ind * M + m]);  // chosen_x
    out[BM + o] = fminf(x[b * N + bi],  w[bi * M + m]);   // chosen_w
}

extern "C" void kernel_launch(void* const* d_in, const int* in_sizes, int n_in,
                              void* d_out, int out_size, void* d_ws, size_t ws_size,
                              hipStream_t stream) {
    const float* x = (const float*)d_in[0];  // (B, N)
    const float* w = (const float*)d_in[1];  // (N, M)
    const float* t = (const float*)d_in[2];  // (B, M)
    float* out = (float*)d_out;

    float* ws = (float*)d_ws;
    // layout (float offsets):
    float*  xT    = ws;                       // 131072
    float*  sum_x = ws + 131072;              // 512
    float*  sum_w = ws + 131584;              // 512
    float*  rel_x = ws + 132096;              // 262144
    float*  swT   = ws + 394240;              // 262144
    float*  pmT   = ws + 656384;              // 262144
    double* psT   = (double*)(ws + 918528);   // 512*514 doubles = 526336 floats
    float*  pxpv  = ws + 1444864;             // px then (aliased) pv

    // big layout = 11.6 MB (Zr=4, Zb=8 -> 4 waves/SIMD); small = 8.6 MB proven-safe
    const bool big = ws_size >= (size_t)13 * 1024 * 1024;
    const int Zr = big ? 4 : 2;
    const int Zb = big ? 8 : 4;
    float* px = pxpv;                                        // Zr*NM floats
    float* pv = pxpv;                                        // Zb*BM floats (after px dead)
    unsigned short* pi = (unsigned short*)(pxpv + (big ? 1048576 : 524288)); // Zb*BM u16

    k_xt   <<<dim3(N / 64, B / 64), dim3(64, 4), 0, stream>>>(x, xT);
    k_sums <<<dim3(16), dim3(64), 0, stream>>>(x, w, sum_x, sum_w);
    k_sortw<<<dim3(M), dim3(512), 0, stream>>>(w, pmT, swT, psT);
    k_relxA<<<dim3(16, 16, Zr), dim3(16, 16), 0, stream>>>(xT, t, px, (B / Zr) / 32);
    k_relxB<<<dim3(NM / 1024), dim3(256), 0, stream>>>(px, sum_x, rel_x, Zr);
    k_bmA2 <<<dim3(16, 8, Zb), dim3(16, 16), 0, stream>>>(xT, rel_x, pv, pi, (N / Zb) / 32);
    k_bmB  <<<dim3(8, 64), dim3(64, 4), 0, stream>>>(x, w, t, sum_w, swT, pmT, psT, pv, pi, out, Zb);
}